// Round 11
// baseline (119.290 us; speedup 1.0000x reference)
//
#include <hip/hip_runtime.h>

#define D 128
#define KK 256    // concatenated K (feat | ah)
#define CH 2048   // edges per scatter chunk
#define PADC 32   // cursor padding in ints (128B line per dst)
#define AHP 136   // LDS ah row stride in ushorts (128 + 8 pad)

typedef __attribute__((ext_vector_type(8))) short short8;
typedef __attribute__((ext_vector_type(4))) float f32x4;
typedef __attribute__((ext_vector_type(2))) float f32x2;

__device__ __forceinline__ ushort f2bf(float x) {  // RNE f32 -> bf16 bits
  union { float f; uint u; } v; v.f = x;
  uint r = v.u + 0x7fffu + ((v.u >> 16) & 1u);
  return (ushort)(r >> 16);
}

// ---------------------------------------------------------------------------
// Fused: feat f32 -> fp8(e4m3) convert (tid < total16, 16 floats/thread)
//      + W convert (tid < D*D)
//      + edge pack (tid < E): packed = (dst<<16)|src  (both < 65536)
//      + scan phase 1 (blocks < nb): intra-block excl scan of (int)in_norm
//        -> offs (dense) and cursorp (one 128B line per dst), raw bsums
// ---------------------------------------------------------------------------
__global__ __launch_bounds__(256) void conv_all(
    const float* __restrict__ feat, uint* __restrict__ featf8, int total16,
    const float* __restrict__ w1, const float* __restrict__ w2,
    ushort* __restrict__ W,
    const float* __restrict__ in_norm, int* __restrict__ offs,
    int* __restrict__ cursorp, int* __restrict__ bsums, int n,
    const int* __restrict__ src, const int* __restrict__ dst,
    uint* __restrict__ packed, int E) {
  int tid = blockIdx.x * 256 + threadIdx.x;
  if (tid < total16) {
    uint f8[4];
#pragma unroll
    for (int t = 0; t < 4; ++t) {
      float4 f = ((const float4*)feat)[tid * 4 + t];
      uint r = __builtin_amdgcn_cvt_pk_fp8_f32(f.x, f.y, 0, false);
      r = (uint)__builtin_amdgcn_cvt_pk_fp8_f32(f.z, f.w, (int)r, true);
      f8[t] = r;
    }
    ((uint4*)featf8)[tid] = make_uint4(f8[0], f8[1], f8[2], f8[3]);
  }
  if (tid < D * D) {
    int o = tid >> 7, k = tid & (D - 1);
    W[o * KK + k]     = f2bf(w1[tid]);
    W[o * KK + D + k] = f2bf(w2[tid]);
  }
  if (tid < E) packed[tid] = ((uint)dst[tid] << 16) | (uint)src[tid];
  int nb = (n + 255) >> 8;
  if ((int)blockIdx.x < nb) {
    __shared__ int tmp[256];
    int t = threadIdx.x;
    int i = blockIdx.x * 256 + t;
    int v = (i < n) ? (int)in_norm[i] : 0;
    tmp[t] = v;
    __syncthreads();
    for (int off = 1; off < 256; off <<= 1) {
      int a = tmp[t];
      int b = (t >= off) ? tmp[t - off] : 0;
      __syncthreads();
      tmp[t] = a + b;
      __syncthreads();
    }
    if (i < n) {
      int intra = tmp[t] - v;  // intra-block exclusive
      offs[i] = intra;
      cursorp[(size_t)i * PADC] = intra;
    }
    if (t == 255) bsums[blockIdx.x] = tmp[255];
  }
}

// exclusive-scan the (<=256) raw block sums into LDS base_s; all 256 threads
__device__ __forceinline__ void scan_bsums(const int* __restrict__ bsums,
                                           int* base_s, int nb) {
  int t = threadIdx.x;
  int raw = (t < nb) ? bsums[t] : 0;
  base_s[t] = raw;
  __syncthreads();
  for (int off = 1; off < 256; off <<= 1) {
    int a = base_s[t];
    int b = (t >= off) ? base_s[t - off] : 0;
    __syncthreads();
    base_s[t] = a + b;
    __syncthreads();
  }
  int excl = base_s[t] - raw;
  __syncthreads();
  base_s[t] = excl;
  __syncthreads();
}

// ---------------------------------------------------------------------------
// XCD-range-partitioned scatter (r = blockIdx&7 ~ XCD round-robin): blocks
// with equal r sweep all edges via packed[], handling only dst in range r.
// Cursors padded one per 128B line -> ~24-long same-line atomic chains
// spread over 3125 independent lines per XCD.
// ---------------------------------------------------------------------------
__global__ __launch_bounds__(256) void scatterx(
    const uint* __restrict__ packed, int* __restrict__ cursorp,
    const int* __restrict__ bsums, ushort* __restrict__ csr,
    int E, int n, int nb) {
  __shared__ int base_s[256];
  scan_bsums(bsums, base_s, nb);
  int r = blockIdx.x & 7;
  int j = blockIdx.x >> 3;
  int e0 = j * CH;
  int e1 = min(e0 + CH, E);
  int lo = (r * n) >> 3;
  int hi = ((r + 1) * n) >> 3;
  for (int e = e0 + (int)threadIdx.x; e < e1; e += 256) {
    uint p = packed[e];
    int v = (int)(p >> 16);
    if (v >= lo && v < hi) {
      int pos = atomicAdd(&cursorp[(size_t)v * PADC], 1) + base_s[v >> 8];
      csr[pos] = (ushort)(p & 0xffffu);
    }
  }
}

// ---------------------------------------------------------------------------
// Fused gather + MFMA GEMM. Block = 4 waves = 64 rows.
// Phase 1: wave wid gathers its 16 rows (fp8 feat, 2 edges/iter, half-wave
//          per edge, 4-deep ILP), /in_norm folded, bf16 into padded LDS.
// Phase 2: MFMA out[m][o] = feat[m]*W[o][0:128] + ah[m]*W[o][128:256] + b.
// Wave only reads LDS rows it wrote; one barrier between phases for safety.
// ---------------------------------------------------------------------------
__global__ __launch_bounds__(256) void gather_gemm(
    const uint* __restrict__ featf8, const ushort* __restrict__ csr,
    const int* __restrict__ offs, const int* __restrict__ cursorp,
    const int* __restrict__ bsums, const float* __restrict__ in_norm,
    const float* __restrict__ feat, const ushort* __restrict__ W,
    const float* __restrict__ b1, const float* __restrict__ b2,
    float* __restrict__ out, int ndst, int nb) {
  __shared__ int base_s[256];
  __shared__ ushort ah[64 * AHP];
  scan_bsums(bsums, base_s, nb);

  int t = threadIdx.x;
  int wid = t >> 6;
  int lane = t & 63;
  int half = lane >> 5;
  int l32 = lane & 31;
  int row0 = blockIdx.x * 64;

  // ---- phase 1: gather 16 rows per wave ----
  for (int q = 0; q < 16; ++q) {
    int row = row0 + wid * 16 + q;
    if (row >= ndst) row = ndst - 1;  // duplicate work on tail block only
    int base = base_s[row >> 8];
    int beg = offs[row] + base;
    int end = cursorp[(size_t)row * PADC] + base;
    float4 a0 = make_float4(0.f, 0.f, 0.f, 0.f);
    float4 a1 = a0;
    int j = beg;
    for (; j + 7 < end; j += 8) {
      uint p[4];
#pragma unroll
      for (int u = 0; u < 4; ++u) {
        int s = csr[j + 2 * u + half];
        p[u] = featf8[s * 32 + l32];
      }
#pragma unroll
      for (int u = 0; u < 4; ++u) {
        f32x2 lo = __builtin_amdgcn_cvt_pk_f32_fp8((int)p[u], false);
        f32x2 hi = __builtin_amdgcn_cvt_pk_f32_fp8((int)p[u], true);
        if (u & 1) {
          a1.x += lo[0]; a1.y += lo[1]; a1.z += hi[0]; a1.w += hi[1];
        } else {
          a0.x += lo[0]; a0.y += lo[1]; a0.z += hi[0]; a0.w += hi[1];
        }
      }
    }
    for (; j + 1 < end; j += 2) {
      int s = csr[j + half];
      uint p = featf8[s * 32 + l32];
      f32x2 lo = __builtin_amdgcn_cvt_pk_f32_fp8((int)p, false);
      f32x2 hi = __builtin_amdgcn_cvt_pk_f32_fp8((int)p, true);
      a0.x += lo[0]; a0.y += lo[1]; a0.z += hi[0]; a0.w += hi[1];
    }
    if (j < end && half == 0) {
      uint p = featf8[(int)csr[j] * 32 + l32];
      f32x2 lo = __builtin_amdgcn_cvt_pk_f32_fp8((int)p, false);
      f32x2 hi = __builtin_amdgcn_cvt_pk_f32_fp8((int)p, true);
      a1.x += lo[0]; a1.y += lo[1]; a1.z += hi[0]; a1.w += hi[1];
    }
    float sx = a0.x + a1.x, sy = a0.y + a1.y;
    float sz = a0.z + a1.z, sw = a0.w + a1.w;
    sx += __shfl_xor(sx, 32);
    sy += __shfl_xor(sy, 32);
    sz += __shfl_xor(sz, 32);
    sw += __shfl_xor(sw, 32);
    if (half == 0) {
      float inv = 1.0f / in_norm[row];
      ushort4 o;
      o.x = f2bf(sx * inv); o.y = f2bf(sy * inv);
      o.z = f2bf(sz * inv); o.w = f2bf(sw * inv);
      *(ushort4*)(&ah[(wid * 16 + q) * AHP + l32 * 4]) = o;
    }
  }
  __syncthreads();

  // ---- phase 2: MFMA ----
  int r = lane & 15;
  int kg = lane >> 4;
  int arow = row0 + wid * 16 + r;
  if (arow >= ndst) arow = ndst - 1;  // clamped lanes' results discarded

  short8 afrag[8];
  const float* fr = feat + (size_t)arow * D;
  const ushort* ar = &ah[(wid * 16 + r) * AHP];
#pragma unroll
  for (int s = 0; s < 4; ++s) {
    float4 lo = *(const float4*)(fr + s * 32 + kg * 8);
    float4 hi = *(const float4*)(fr + s * 32 + kg * 8 + 4);
    short8 tt;
    tt[0] = (short)f2bf(lo.x); tt[1] = (short)f2bf(lo.y);
    tt[2] = (short)f2bf(lo.z); tt[3] = (short)f2bf(lo.w);
    tt[4] = (short)f2bf(hi.x); tt[5] = (short)f2bf(hi.y);
    tt[6] = (short)f2bf(hi.z); tt[7] = (short)f2bf(hi.w);
    afrag[s] = tt;
    afrag[4 + s] = *(const short8*)(ar + s * 32 + kg * 8);
  }

  f32x4 acc[8];
#pragma unroll
  for (int n2 = 0; n2 < 8; ++n2) acc[n2] = (f32x4){0.f, 0.f, 0.f, 0.f};

#pragma unroll
  for (int n2 = 0; n2 < 8; ++n2) {
    const ushort* wr = W + (size_t)(n2 * 16 + r) * KK;
#pragma unroll
    for (int s = 0; s < 8; ++s) {
      short8 bfrag = *(const short8*)(wr + s * 32 + kg * 8);
      acc[n2] = __builtin_amdgcn_mfma_f32_16x16x32_bf16(afrag[s], bfrag, acc[n2], 0, 0, 0);
    }
  }

#pragma unroll
  for (int n2 = 0; n2 < 8; ++n2) {
    int col = n2 * 16 + r;
    float bb = b1[col] + b2[col];
#pragma unroll
    for (int q = 0; q < 4; ++q) {
      int orow = row0 + wid * 16 + kg * 4 + q;
      if (orow < ndst) out[(size_t)orow * D + col] = acc[n2][q] + bb;
    }
  }
}

extern "C" void kernel_launch(void* const* d_in, const int* in_sizes, int n_in,
                              void* d_out, int out_size, void* d_ws, size_t ws_size,
                              hipStream_t stream) {
  const float* feat    = (const float*)d_in[0];
  const float* in_norm = (const float*)d_in[1];
  const float* w1      = (const float*)d_in[2];
  const float* b1      = (const float*)d_in[3];
  const float* w2      = (const float*)d_in[4];
  const float* b2      = (const float*)d_in[5];
  const int*   src     = (const int*)d_in[6];
  const int*   dst     = (const int*)d_in[7];
  float*       out     = (float*)d_out;

  int E    = in_sizes[6];
  int ndst = in_sizes[1];
  int featn = in_sizes[0];  // N_SRC * D

  // workspace layout (16B-aligned pieces)
  char* ws = (char*)d_ws;
  uint* featf8 = (uint*)ws;                                    // featn fp8
  size_t off = (size_t)featn;
  ushort* W = (ushort*)(ws + off);    off += (size_t)D * KK * sizeof(ushort);
  uint* packed = (uint*)(ws + off);   off += (size_t)E * sizeof(uint);
  ushort* csr = (ushort*)(ws + off);  off += (((size_t)E + 7) & ~7ull) * sizeof(ushort);
  int* offs = (int*)(ws + off);       off += (size_t)ndst * sizeof(int);
  int* cursorp = (int*)(ws + off);    off += (size_t)ndst * PADC * sizeof(int);
  int* bsums = (int*)(ws + off);

  int total16 = featn / 16;                    // 16 floats per thread
  int nb = (ndst + 255) / 256;                 // scan blocks (98 <= 256)
  int cblocks = (E + 255) / 256;               // covers packing sweep
  if (cblocks < (total16 + 255) / 256) cblocks = (total16 + 255) / 256;
  if (cblocks < nb) cblocks = nb;

  conv_all<<<cblocks, 256, 0, stream>>>(
      feat, featf8, total16, w1, w2, W, in_norm, offs, cursorp, bsums, ndst,
      src, dst, packed, E);
  int nj = (E + CH - 1) / CH;
  scatterx<<<8 * nj, 256, 0, stream>>>(packed, cursorp, bsums, csr, E, ndst, nb);
  gather_gemm<<<(ndst + 63) / 64, 256, 0, stream>>>(
      featf8, csr, offs, cursorp, bsums, in_norm, feat, W, b1, b2,
      out, ndst, nb);
}

// Round 12
// 87.318 us; speedup vs baseline: 1.3662x; 1.3662x over previous
//
#include <hip/hip_runtime.h>

#define D 128
#define KK 256    // concatenated K (feat | ah)
#define CH 2048   // edges per scatter chunk
#define PADC 32   // cursor padding in ints (128B line per dst)

typedef __attribute__((ext_vector_type(8))) short short8;
typedef __attribute__((ext_vector_type(4))) float f32x4;
typedef __attribute__((ext_vector_type(2))) float f32x2;

__device__ __forceinline__ ushort f2bf(float x) {  // RNE f32 -> bf16 bits
  union { float f; uint u; } v; v.f = x;
  uint r = v.u + 0x7fffu + ((v.u >> 16) & 1u);
  return (ushort)(r >> 16);
}

// ---------------------------------------------------------------------------
// Fused: feat f32 -> fp8(e4m3) convert (tid < total16, 16 floats/thread)
//      + W convert (tid < D*D)
//      + edge pack (tid < E): packed = (dst<<16)|src  (both < 65536)
//      + scan phase 1 (blocks < nb): intra-block excl scan of (int)in_norm
//        -> offs (dense) and cursorp (one 128B line per dst), raw bsums
// ---------------------------------------------------------------------------
__global__ __launch_bounds__(256) void conv_all(
    const float* __restrict__ feat, uint* __restrict__ featf8, int total16,
    const float* __restrict__ w1, const float* __restrict__ w2,
    ushort* __restrict__ W,
    const float* __restrict__ in_norm, int* __restrict__ offs,
    int* __restrict__ cursorp, int* __restrict__ bsums, int n,
    const int* __restrict__ src, const int* __restrict__ dst,
    uint* __restrict__ packed, int E) {
  int tid = blockIdx.x * 256 + threadIdx.x;
  if (tid < total16) {
    uint f8[4];
#pragma unroll
    for (int t = 0; t < 4; ++t) {
      float4 f = ((const float4*)feat)[tid * 4 + t];
      uint r = __builtin_amdgcn_cvt_pk_fp8_f32(f.x, f.y, 0, false);
      r = (uint)__builtin_amdgcn_cvt_pk_fp8_f32(f.z, f.w, (int)r, true);
      f8[t] = r;
    }
    ((uint4*)featf8)[tid] = make_uint4(f8[0], f8[1], f8[2], f8[3]);
  }
  if (tid < D * D) {
    int o = tid >> 7, k = tid & (D - 1);
    W[o * KK + k]     = f2bf(w1[tid]);
    W[o * KK + D + k] = f2bf(w2[tid]);
  }
  if (tid < E) packed[tid] = ((uint)dst[tid] << 16) | (uint)src[tid];
  int nb = (n + 255) >> 8;
  if ((int)blockIdx.x < nb) {
    __shared__ int tmp[256];
    int t = threadIdx.x;
    int i = blockIdx.x * 256 + t;
    int v = (i < n) ? (int)in_norm[i] : 0;
    tmp[t] = v;
    __syncthreads();
    for (int off = 1; off < 256; off <<= 1) {
      int a = tmp[t];
      int b = (t >= off) ? tmp[t - off] : 0;
      __syncthreads();
      tmp[t] = a + b;
      __syncthreads();
    }
    if (i < n) {
      int intra = tmp[t] - v;  // intra-block exclusive
      offs[i] = intra;
      cursorp[(size_t)i * PADC] = intra;
    }
    if (t == 255) bsums[blockIdx.x] = tmp[255];
  }
}

// exclusive-scan the (<=256) raw block sums into LDS base_s; all 256 threads
__device__ __forceinline__ void scan_bsums(const int* __restrict__ bsums,
                                           int* base_s, int nb) {
  int t = threadIdx.x;
  int raw = (t < nb) ? bsums[t] : 0;
  base_s[t] = raw;
  __syncthreads();
  for (int off = 1; off < 256; off <<= 1) {
    int a = base_s[t];
    int b = (t >= off) ? base_s[t - off] : 0;
    __syncthreads();
    base_s[t] = a + b;
    __syncthreads();
  }
  int excl = base_s[t] - raw;
  __syncthreads();
  base_s[t] = excl;
  __syncthreads();
}

// ---------------------------------------------------------------------------
// XCD-range-partitioned scatter (r = blockIdx&7 ~ XCD round-robin): blocks
// with equal r sweep all edges via packed[], handling only dst in range r.
// Cursors padded one per 128B line.
// ---------------------------------------------------------------------------
__global__ __launch_bounds__(256) void scatterx(
    const uint* __restrict__ packed, int* __restrict__ cursorp,
    const int* __restrict__ bsums, ushort* __restrict__ csr,
    int E, int n, int nb) {
  __shared__ int base_s[256];
  scan_bsums(bsums, base_s, nb);
  int r = blockIdx.x & 7;
  int j = blockIdx.x >> 3;
  int e0 = j * CH;
  int e1 = min(e0 + CH, E);
  int lo = (r * n) >> 3;
  int hi = ((r + 1) * n) >> 3;
  for (int e = e0 + (int)threadIdx.x; e < e1; e += 256) {
    uint p = packed[e];
    int v = (int)(p >> 16);
    if (v >= lo && v < hi) {
      int pos = atomicAdd(&cursorp[(size_t)v * PADC], 1) + base_s[v >> 8];
      csr[pos] = (ushort)(p & 0xffffu);
    }
  }
}

// ---------------------------------------------------------------------------
// dst-major gather from fp8 feat; one wave per row (max occupancy for
// latency hiding), 2 edges/iter (half-wave per edge, 1 dword = 4 fp8/lane),
// f32 accumulation, shfl_xor(32) combine, /in_norm folded, ah written bf16.
// ---------------------------------------------------------------------------
__global__ __launch_bounds__(256) void gather_rows(
    const uint* __restrict__ featf8, const ushort* __restrict__ csr,
    const int* __restrict__ offs, const int* __restrict__ cursorp,
    const int* __restrict__ bsums, const float* __restrict__ in_norm,
    ushort* __restrict__ ahb, int ndst, int nb) {
  __shared__ int base_s[256];
  scan_bsums(bsums, base_s, nb);
  int row = blockIdx.x * 4 + (threadIdx.x >> 6);
  if (row >= ndst) return;
  int lane = threadIdx.x & 63;
  int half = lane >> 5;
  int l32 = lane & 31;
  int base = base_s[row >> 8];
  int beg = offs[row] + base;
  int end = cursorp[(size_t)row * PADC] + base;
  float4 a0 = make_float4(0.f, 0.f, 0.f, 0.f);
  float4 a1 = a0;
  int j = beg;
  for (; j + 7 < end; j += 8) {  // 8 edges per iter, 4 loads/lane in flight
    uint p[4];
#pragma unroll
    for (int t = 0; t < 4; ++t) {
      int u = csr[j + 2 * t + half];
      p[t] = featf8[u * 32 + l32];
    }
#pragma unroll
    for (int t = 0; t < 4; ++t) {
      f32x2 lo = __builtin_amdgcn_cvt_pk_f32_fp8((int)p[t], false);
      f32x2 hi = __builtin_amdgcn_cvt_pk_f32_fp8((int)p[t], true);
      if (t & 1) {
        a1.x += lo[0]; a1.y += lo[1]; a1.z += hi[0]; a1.w += hi[1];
      } else {
        a0.x += lo[0]; a0.y += lo[1]; a0.z += hi[0]; a0.w += hi[1];
      }
    }
  }
  for (; j + 1 < end; j += 2) {
    int u = csr[j + half];
    uint p = featf8[u * 32 + l32];
    f32x2 lo = __builtin_amdgcn_cvt_pk_f32_fp8((int)p, false);
    f32x2 hi = __builtin_amdgcn_cvt_pk_f32_fp8((int)p, true);
    a0.x += lo[0]; a0.y += lo[1]; a0.z += hi[0]; a0.w += hi[1];
  }
  if (j < end && half == 0) {  // odd tail: half 0 only
    uint p = featf8[(int)csr[j] * 32 + l32];
    f32x2 lo = __builtin_amdgcn_cvt_pk_f32_fp8((int)p, false);
    f32x2 hi = __builtin_amdgcn_cvt_pk_f32_fp8((int)p, true);
    a1.x += lo[0]; a1.y += lo[1]; a1.z += hi[0]; a1.w += hi[1];
  }
  float sx = a0.x + a1.x, sy = a0.y + a1.y;
  float sz = a0.z + a1.z, sw = a0.w + a1.w;
  sx += __shfl_xor(sx, 32);
  sy += __shfl_xor(sy, 32);
  sz += __shfl_xor(sz, 32);
  sw += __shfl_xor(sw, 32);
  if (half == 0) {
    float inv = 1.0f / in_norm[row];
    ushort4 o;
    o.x = f2bf(sx * inv); o.y = f2bf(sy * inv);
    o.z = f2bf(sz * inv); o.w = f2bf(sw * inv);
    ((ushort4*)(ahb + (size_t)row * D))[l32] = o;
  }
}

// ---------------------------------------------------------------------------
// MFMA GEMM: out[m][o] = sum_k feat[m][k]*W[o][k] (k<128, f32 read + RNE)
//                      + sum_k ahb[m][k]*W[o][128+k] + b1[o]+b2[o]
// Block = 4 waves = 64 rows; wave = 16 rows x 128 cols; K=256 in 8 steps.
// ---------------------------------------------------------------------------
__global__ __launch_bounds__(256) void gemm_mfma(
    const float* __restrict__ feat, const ushort* __restrict__ ahb,
    const ushort* __restrict__ W, const float* __restrict__ b1,
    const float* __restrict__ b2, float* __restrict__ out, int ndst) {
  int wid = threadIdx.x >> 6;
  int lane = threadIdx.x & 63;
  int row0 = blockIdx.x * 64 + wid * 16;
  int r = lane & 15;
  int kg = lane >> 4;
  int arow = row0 + r;
  if (arow >= ndst) arow = ndst - 1;  // clamped lanes' results are discarded

  short8 afrag[8];
  const float* fr = feat + (size_t)arow * D;
  const ushort* ar = ahb + (size_t)arow * D;
#pragma unroll
  for (int s = 0; s < 4; ++s) {
    float4 lo = *(const float4*)(fr + s * 32 + kg * 8);
    float4 hi = *(const float4*)(fr + s * 32 + kg * 8 + 4);
    short8 t;
    t[0] = (short)f2bf(lo.x); t[1] = (short)f2bf(lo.y);
    t[2] = (short)f2bf(lo.z); t[3] = (short)f2bf(lo.w);
    t[4] = (short)f2bf(hi.x); t[5] = (short)f2bf(hi.y);
    t[6] = (short)f2bf(hi.z); t[7] = (short)f2bf(hi.w);
    afrag[s] = t;
    afrag[4 + s] = *(const short8*)(ar + s * 32 + kg * 8);
  }

  f32x4 acc[8];
#pragma unroll
  for (int n = 0; n < 8; ++n) acc[n] = (f32x4){0.f, 0.f, 0.f, 0.f};

#pragma unroll
  for (int n = 0; n < 8; ++n) {
    const ushort* wr = W + (size_t)(n * 16 + r) * KK;
#pragma unroll
    for (int s = 0; s < 8; ++s) {
      short8 bfrag = *(const short8*)(wr + s * 32 + kg * 8);
      acc[n] = __builtin_amdgcn_mfma_f32_16x16x32_bf16(afrag[s], bfrag, acc[n], 0, 0, 0);
    }
  }

#pragma unroll
  for (int n = 0; n < 8; ++n) {
    int col = n * 16 + r;
    float bb = b1[col] + b2[col];
#pragma unroll
    for (int q = 0; q < 4; ++q) {
      int orow = row0 + kg * 4 + q;
      if (orow < ndst) out[(size_t)orow * D + col] = acc[n][q] + bb;
    }
  }
}

extern "C" void kernel_launch(void* const* d_in, const int* in_sizes, int n_in,
                              void* d_out, int out_size, void* d_ws, size_t ws_size,
                              hipStream_t stream) {
  const float* feat    = (const float*)d_in[0];
  const float* in_norm = (const float*)d_in[1];
  const float* w1      = (const float*)d_in[2];
  const float* b1      = (const float*)d_in[3];
  const float* w2      = (const float*)d_in[4];
  const float* b2      = (const float*)d_in[5];
  const int*   src     = (const int*)d_in[6];
  const int*   dst     = (const int*)d_in[7];
  float*       out     = (float*)d_out;

  int E    = in_sizes[6];
  int ndst = in_sizes[1];
  int featn = in_sizes[0];  // N_SRC * D

  // workspace layout (16B-aligned pieces)
  char* ws = (char*)d_ws;
  uint* featf8 = (uint*)ws;                                    // featn fp8
  size_t off = (size_t)featn;
  ushort* ahb = (ushort*)(ws + off);  off += (size_t)ndst * D * sizeof(ushort);
  ushort* W = (ushort*)(ws + off);    off += (size_t)D * KK * sizeof(ushort);
  uint* packed = (uint*)(ws + off);   off += (size_t)E * sizeof(uint);
  ushort* csr = (ushort*)(ws + off);  off += (((size_t)E + 7) & ~7ull) * sizeof(ushort);
  int* offs = (int*)(ws + off);       off += (size_t)ndst * sizeof(int);
  int* cursorp = (int*)(ws + off);    off += (size_t)ndst * PADC * sizeof(int);
  int* bsums = (int*)(ws + off);

  int total16 = featn / 16;                    // 16 floats per thread
  int nb = (ndst + 255) / 256;                 // scan blocks (98 <= 256)
  int cblocks = (E + 255) / 256;               // covers packing sweep
  if (cblocks < (total16 + 255) / 256) cblocks = (total16 + 255) / 256;
  if (cblocks < nb) cblocks = nb;

  conv_all<<<cblocks, 256, 0, stream>>>(
      feat, featf8, total16, w1, w2, W, in_norm, offs, cursorp, bsums, ndst,
      src, dst, packed, E);
  int nj = (E + CH - 1) / CH;
  scatterx<<<8 * nj, 256, 0, stream>>>(packed, cursorp, bsums, csr, E, ndst, nb);
  gather_rows<<<(ndst + 3) / 4, 256, 0, stream>>>(
      featf8, csr, offs, cursorp, bsums, in_norm, ahb, ndst, nb);
  gemm_mfma<<<(ndst + 63) / 64, 256, 0, stream>>>(
      feat, ahb, W, b1, b2, out, ndst);
}